// Round 8
// baseline (363.172 us; speedup 1.0000x reference)
//
#include <hip/hip_runtime.h>

#define FEAT 128
#define HID 32
#define EMB 16
#define NEG 0.2f

// CSR-build binning parameters. Assumes Nn <= 2^17 (src id fits 17 bits) and
// Nn <= NBMAX*BIN_NODES. For this problem Nn=100000, E=3.2M.
#define BSH 8                 // 256 nodes per bin
#define BIN_NODES 256
#define NBMAX 400             // >= ceil(100000/256)=391
#define CH 8192               // edges per partition block
#define CAP 12288             // LDS staging capacity per bin (mean 8192, +45 sigma)
#define SRCBITS 17
#define SRCMASK 0x1FFFF

__device__ __forceinline__ float lrelu(float a) { return a > 0.0f ? a : NEG * a; }

__global__ __launch_bounds__(256) void k_zero_int(int* p, int n) {
    int i = (int)(blockIdx.x * 256 + threadIdx.x);
    if (i < n) p[i] = 0;
}

// ---- CSR build, phase 1: per-bin edge counts (dst >> BSH) ----
__global__ __launch_bounds__(256) void k_bincnt(const int* __restrict__ ei, int E_,
                                                int Nn, int* __restrict__ binCnt) {
    __shared__ int h[NBMAX];
    int nb = (Nn + BIN_NODES - 1) >> BSH;
    for (int i = threadIdx.x; i < nb; i += 256) h[i] = 0;
    __syncthreads();
    int stride = (int)(gridDim.x * 256);
    for (int i = (int)(blockIdx.x * 256 + threadIdx.x); i < E_; i += stride)
        atomicAdd(&h[ei[(size_t)E_ + i] >> BSH], 1);
    __syncthreads();
    for (int i = threadIdx.x; i < nb; i += 256)
        if (h[i]) atomicAdd(&binCnt[i], h[i]);
}

// ---- phase 2: scan bin counts -> binstart, init bin_pos; rowptr[Nn]=E ----
__global__ __launch_bounds__(512) void k_binscan(const int* __restrict__ binCnt,
                                                 int* __restrict__ binstart,
                                                 int* __restrict__ bin_pos,
                                                 int* __restrict__ rowptr,
                                                 int Nn, int E_) {
    __shared__ int s[512];
    int nb = (Nn + BIN_NODES - 1) >> BSH;
    int t = (int)threadIdx.x;
    s[t] = (t < nb) ? binCnt[t] : 0;
    __syncthreads();
    for (int off = 1; off < 512; off <<= 1) {
        int v = (t >= off) ? s[t - off] : 0;
        __syncthreads();
        s[t] += v;
        __syncthreads();
    }
    if (t <= nb) binstart[t] = (t == 0) ? 0 : s[t - 1];
    if (t < nb) bin_pos[t] = (t == 0) ? 0 : s[t - 1];
    if (t == 0) rowptr[Nn] = E_;
}

// ---- phase 3: multisplit partition. Stage chunk in LDS grouped by bin, then
// write contiguous per-bin runs of packed words ((dst&255)<<17 | src). ----
__global__ __launch_bounds__(1024) void k_part(const int* __restrict__ ei, int E_,
                                               int Nn, int* __restrict__ bin_pos,
                                               int* __restrict__ packed) {
    __shared__ int hist[NBMAX];
    __shared__ int lofs[NBMAX];
    __shared__ int pos[NBMAX];
    __shared__ int gbase[NBMAX];
    __shared__ int sscan[512];
    __shared__ int staged[CH];
    __shared__ unsigned short sbin[CH];
    int nb = (Nn + BIN_NODES - 1) >> BSH;
    int base = (int)(blockIdx.x * CH);
    int nE = min(CH, E_ - base);
    int t = (int)threadIdx.x;
    for (int i = t; i < nb; i += 1024) hist[i] = 0;
    __syncthreads();

    int myw[CH / 1024];
    int myb[CH / 1024];
#pragma unroll
    for (int k = 0; k < CH / 1024; ++k) {
        int i = t + k * 1024;
        int w = 0, b_ = -1;
        if (i < nE) {
            int s_ = ei[base + i];
            int d_ = ei[(size_t)E_ + base + i];
            b_ = d_ >> BSH;
            w = ((d_ & (BIN_NODES - 1)) << SRCBITS) | s_;
            atomicAdd(&hist[b_], 1);
        }
        myw[k] = w;
        myb[k] = b_;
    }
    __syncthreads();
    // exclusive scan of hist over 512-wide region
    if (t < 512) sscan[t] = (t < nb) ? hist[t] : 0;
    __syncthreads();
    for (int off = 1; off < 512; off <<= 1) {
        int v = 0;
        if (t < 512 && t >= off) v = sscan[t - off];
        __syncthreads();
        if (t < 512) sscan[t] += v;
        __syncthreads();
    }
    for (int i = t; i < nb; i += 1024) {
        int ex = (i == 0) ? 0 : sscan[i - 1];
        lofs[i] = ex;
        pos[i] = ex;
    }
    __syncthreads();
    // scatter into LDS grouped by bin
#pragma unroll
    for (int k = 0; k < CH / 1024; ++k) {
        if (myb[k] >= 0) {
            int p = atomicAdd(&pos[myb[k]], 1);
            staged[p] = myw[k];
            sbin[p] = (unsigned short)myb[k];
        }
    }
    __syncthreads();
    // reserve global runs (one atomic per non-empty bin)
    for (int i = t; i < nb; i += 1024)
        gbase[i] = hist[i] ? atomicAdd(&bin_pos[i], hist[i]) : 0;
    __syncthreads();
    // coalesced write-out of per-bin runs
    for (int i = t; i < nE; i += 1024) {
        int b_ = sbin[i];
        packed[gbase[b_] + (i - lofs[b_])] = staged[i];
    }
}

// ---- phase 4: per-bin build. LDS scatter -> per-node-ordered FULL WORDS
// (keeps (dstlow<<17)|src so k_wgt can recover dst), in place over packed.
// Writes the bin's slice of rowptr. scratch used only in the overflow path.
__global__ __launch_bounds__(1024) void k_build(const int* __restrict__ binstart,
                                                int Nn, int E_,
                                                int* __restrict__ packed,
                                                int* __restrict__ rowptr,
                                                int* __restrict__ scratch) {
    __shared__ int ncnt[BIN_NODES];
    __shared__ int npos[BIN_NODES];
    __shared__ int sscan[BIN_NODES];
    __shared__ int csr_l[CAP];
    int b = (int)blockIdx.x;
    int s = binstart[b], e = binstart[b + 1];
    int cnt = e - s;
    int nb0 = b << BSH;
    int nodes = min(BIN_NODES, Nn - nb0);
    int t = (int)threadIdx.x;
    if (t < BIN_NODES) ncnt[t] = 0;
    __syncthreads();
    for (int i = t; i < cnt; i += 1024) atomicAdd(&ncnt[(packed[s + i] >> SRCBITS) & 255], 1);
    __syncthreads();
    if (t < BIN_NODES) sscan[t] = ncnt[t];
    __syncthreads();
    for (int off = 1; off < BIN_NODES; off <<= 1) {
        int v = 0;
        if (t < BIN_NODES && t >= off) v = sscan[t - off];
        __syncthreads();
        if (t < BIN_NODES) sscan[t] += v;
        __syncthreads();
    }
    if (t < BIN_NODES) {
        int ex = (t == 0) ? 0 : sscan[t - 1];
        npos[t] = ex;
        if (t < nodes) rowptr[nb0 + t] = s + ex;
    }
    __syncthreads();
    if (cnt <= CAP) {
        for (int i = t; i < cnt; i += 1024) {
            int w = packed[s + i];
            int p = atomicAdd(&npos[(w >> SRCBITS) & 255], 1);
            csr_l[p] = w;                       // keep full word
        }
        __syncthreads();
        for (int i = t; i < cnt; i += 1024) packed[s + i] = csr_l[i];
    } else {
        // overflow fallback: stage via global scratch, then in-place scatter
        for (int i = t; i < cnt; i += 1024) scratch[s + i] = packed[s + i];
        __syncthreads();
        for (int i = t; i < cnt; i += 1024) {
            int w = scratch[s + i];
            int p = atomicAdd(&npos[(w >> SRCBITS) & 255], 1);
            packed[s + p] = w;                  // keep full word
        }
    }
}

// h1 = x @ W1 ; als/ald.  ONE ROW PER THREAD. W1 accesses wave-uniform ->
// scalarized to s_load; no LDS, no shuffles.
__global__ __launch_bounds__(256) void k_h1(
    const float* __restrict__ x, const float* __restrict__ W1,
    const float* __restrict__ a_s, const float* __restrict__ a_d,
    float* __restrict__ h1, float* __restrict__ als, float* __restrict__ ald, int Nn)
{
    int row = (int)(blockIdx.x * 256 + threadIdx.x);
    if (row >= Nn) return;
    const float4* xr = (const float4*)(x + (size_t)row * FEAT);
    float acc[HID];
#pragma unroll
    for (int c = 0; c < HID; ++c) acc[c] = 0.0f;
#pragma unroll 4
    for (int k4 = 0; k4 < FEAT / 4; ++k4) {
        float4 xv = xr[k4];
        const float* Wr = W1 + k4 * 4 * HID;   // wave-uniform -> s_load
#pragma unroll
        for (int c = 0; c < HID; ++c)
            acc[c] += xv.x * Wr[c] + xv.y * Wr[HID + c]
                    + xv.z * Wr[2 * HID + c] + xv.w * Wr[3 * HID + c];
    }
    float4* hr = (float4*)(h1 + (size_t)row * HID);
    float ps = 0.0f, pd = 0.0f;
#pragma unroll
    for (int c4 = 0; c4 < HID / 4; ++c4) {
        float4 hv;
        hv.x = acc[4 * c4 + 0]; hv.y = acc[4 * c4 + 1];
        hv.z = acc[4 * c4 + 2]; hv.w = acc[4 * c4 + 3];
        hr[c4] = hv;
        ps += hv.x * a_s[4 * c4 + 0] + hv.y * a_s[4 * c4 + 1]
            + hv.z * a_s[4 * c4 + 2] + hv.w * a_s[4 * c4 + 3];
        pd += hv.x * a_d[4 * c4 + 0] + hv.y * a_d[4 * c4 + 1]
            + hv.z * a_d[4 * c4 + 2] + hv.w * a_d[4 * c4 + 3];
    }
    als[row] = ps;
    ald[row] = pd;
}

// ---- edge-parallel weight precompute: one block per dst-bin; dst recovered
// from packed word's high bits. als gather is L2-hot (400 KB), ald is L1-hot
// (256 values per bin). Coalesced packed read, coalesced wbuf write. ----
__global__ __launch_bounds__(1024) void k_wgt(const int* __restrict__ binstart,
                                              const int* __restrict__ packed,
                                              const float* __restrict__ als,
                                              const float* __restrict__ ald,
                                              float* __restrict__ wbuf) {
    int b = (int)blockIdx.x;
    int s = binstart[b], e = binstart[b + 1];
    int nb0 = b << BSH;
    for (int i = s + (int)threadIdx.x; i < e; i += 1024) {
        int w = packed[i];
        int src = w & SRCMASK;
        int d = nb0 + ((w >> SRCBITS) & 255);
        wbuf[i] = __expf(lrelu(als[src] + ald[d]));
    }
}

// layer-1 gather-aggregate + norm + relu + (g @ W2) + als2/ald2, fused.
// 8 lanes per node, float4 features. HASW: weights precomputed in wbuf ->
// per 4-edge iter: 1 int4 + 1 float4 + 4 gathers, zero exp. Loop peeled to
// 16B alignment for the vector loads.
template<bool HASW>
__global__ __launch_bounds__(256) void k_agg1(
    const int* __restrict__ rowptr, const int* __restrict__ csr,
    const float* __restrict__ wbuf,
    const float* __restrict__ h1, const float* __restrict__ als,
    const float* __restrict__ ald, const float* __restrict__ b1,
    const float* __restrict__ W2, const float* __restrict__ a_s2,
    const float* __restrict__ a_d2,
    float* __restrict__ h2, float* __restrict__ als2, float* __restrict__ ald2, int Nn)
{
    int n = (int)(blockIdx.x * 32 + (threadIdx.x >> 3));
    if (n >= Nn) return;
    int l = threadIdx.x & 7;                   // lane in 8-lane group
    const float4* h1p = (const float4*)h1;     // row s = elems [s*8 .. s*8+7]
    float aldn = ald[n];
    float wself = __expf(lrelu(als[n] + aldn));
    float4 sv = h1p[(size_t)n * 8 + l];
    float s0x = wself * sv.x, s0y = wself * sv.y;
    float s0z = wself * sv.z, s0w = wself * sv.w;
    float s1x = 0, s1y = 0, s1z = 0, s1w = 0;
    float s2x = 0, s2y = 0, s2z = 0, s2w = 0;
    float s3x = 0, s3y = 0, s3z = 0, s3w = 0;
    float den = wself;
    int e = rowptr[n], e1 = rowptr[n + 1];
    for (; e < e1 && (e & 3); ++e) {           // peel to 16B alignment
        int word = csr[e];
        int s = word & SRCMASK;
        float we;
        if constexpr (HASW) we = wbuf[e];
        else we = __expf(lrelu(als[s] + aldn));
        float4 f = h1p[(size_t)s * 8 + l];
        s0x += we * f.x; s0y += we * f.y; s0z += we * f.z; s0w += we * f.w;
        den += we;
    }
    for (; e + 4 <= e1; e += 4) {
        int4 c4 = *(const int4*)(csr + e);
        int i0 = c4.x & SRCMASK, i1 = c4.y & SRCMASK;
        int i2 = c4.z & SRCMASK, i3 = c4.w & SRCMASK;
        float w0, w1, w2, w3;
        if constexpr (HASW) {
            float4 w4 = *(const float4*)(wbuf + e);
            w0 = w4.x; w1 = w4.y; w2 = w4.z; w3 = w4.w;
        } else {
            w0 = __expf(lrelu(als[i0] + aldn));
            w1 = __expf(lrelu(als[i1] + aldn));
            w2 = __expf(lrelu(als[i2] + aldn));
            w3 = __expf(lrelu(als[i3] + aldn));
        }
        float4 f0 = h1p[(size_t)i0 * 8 + l];
        float4 f1 = h1p[(size_t)i1 * 8 + l];
        float4 f2 = h1p[(size_t)i2 * 8 + l];
        float4 f3 = h1p[(size_t)i3 * 8 + l];
        s0x += w0 * f0.x; s0y += w0 * f0.y; s0z += w0 * f0.z; s0w += w0 * f0.w;
        s1x += w1 * f1.x; s1y += w1 * f1.y; s1z += w1 * f1.z; s1w += w1 * f1.w;
        s2x += w2 * f2.x; s2y += w2 * f2.y; s2z += w2 * f2.z; s2w += w2 * f2.w;
        s3x += w3 * f3.x; s3y += w3 * f3.y; s3z += w3 * f3.z; s3w += w3 * f3.w;
        den += (w0 + w1) + (w2 + w3);
    }
    for (; e < e1; ++e) {                      // tail
        int word = csr[e];
        int s = word & SRCMASK;
        float we;
        if constexpr (HASW) we = wbuf[e];
        else we = __expf(lrelu(als[s] + aldn));
        float4 f = h1p[(size_t)s * 8 + l];
        s0x += we * f.x; s0y += we * f.y; s0z += we * f.z; s0w += we * f.w;
        den += we;
    }
    float inv = 1.0f / den;
    float gx = fmaxf((s0x + s1x + s2x + s3x) * inv + b1[4 * l + 0], 0.0f);
    float gy = fmaxf((s0y + s1y + s2y + s3y) * inv + b1[4 * l + 1], 0.0f);
    float gz = fmaxf((s0z + s1z + s2z + s3z) * inv + b1[4 * l + 2], 0.0f);
    float gw = fmaxf((s0w + s1w + s2w + s3w) * inv + b1[4 * l + 3], 0.0f);
    // h2[n][j] = sum_t g[t] * W2[t][j]; lane l computes cols l and l+8.
    float hc0 = 0.0f, hc1 = 0.0f;
#pragma unroll
    for (int tt = 0; tt < 8; ++tt) {
        float bx = __shfl(gx, tt, 8);
        float by = __shfl(gy, tt, 8);
        float bz = __shfl(gz, tt, 8);
        float bw = __shfl(gw, tt, 8);
        const float* wp = &W2[(4 * tt) * EMB];
        hc0 += bx * wp[l] + by * wp[EMB + l]
             + bz * wp[2 * EMB + l] + bw * wp[3 * EMB + l];
        hc1 += bx * wp[l + 8] + by * wp[EMB + l + 8]
             + bz * wp[2 * EMB + l + 8] + bw * wp[3 * EMB + l + 8];
    }
    h2[(size_t)n * EMB + l] = hc0;
    h2[(size_t)n * EMB + l + 8] = hc1;
    float ps = hc0 * a_s2[l] + hc1 * a_s2[l + 8];
    float pd = hc0 * a_d2[l] + hc1 * a_d2[l + 8];
    for (int m = 1; m < 8; m <<= 1) {
        ps += __shfl_xor(ps, m, 8);
        pd += __shfl_xor(pd, m, 8);
    }
    if (l == 0) { als2[n] = ps; ald2[n] = pd; }
}

// layer-2 gather-aggregate + bias. 8 lanes per node, float2 features (the
// 4-lane variant regressed in round 7 -> reverted), same HASW scheme.
template<bool HASW>
__global__ __launch_bounds__(256) void k_agg2(
    const int* __restrict__ rowptr, const int* __restrict__ csr,
    const float* __restrict__ wbuf,
    const float* __restrict__ h2, const float* __restrict__ als,
    const float* __restrict__ ald, const float* __restrict__ b2,
    float* __restrict__ out, int Nn)
{
    int n = (int)(blockIdx.x * 32 + (threadIdx.x >> 3));
    if (n >= Nn) return;
    int l = threadIdx.x & 7;                   // lane in 8-lane group
    const float2* h2p = (const float2*)h2;     // row s = elems [s*8 .. s*8+7]
    float aldn = ald[n];
    float wself = __expf(lrelu(als[n] + aldn));
    float2 sv = h2p[(size_t)n * 8 + l];
    float s0x = wself * sv.x, s0y = wself * sv.y;
    float s1x = 0, s1y = 0, s2x = 0, s2y = 0, s3x = 0, s3y = 0;
    float den = wself;
    int e = rowptr[n], e1 = rowptr[n + 1];
    for (; e < e1 && (e & 3); ++e) {           // peel to 16B alignment
        int word = csr[e];
        int s = word & SRCMASK;
        float we;
        if constexpr (HASW) we = wbuf[e];
        else we = __expf(lrelu(als[s] + aldn));
        float2 f = h2p[(size_t)s * 8 + l];
        s0x += we * f.x; s0y += we * f.y;
        den += we;
    }
    for (; e + 4 <= e1; e += 4) {
        int4 c4 = *(const int4*)(csr + e);
        int i0 = c4.x & SRCMASK, i1 = c4.y & SRCMASK;
        int i2 = c4.z & SRCMASK, i3 = c4.w & SRCMASK;
        float w0, w1, w2, w3;
        if constexpr (HASW) {
            float4 w4 = *(const float4*)(wbuf + e);
            w0 = w4.x; w1 = w4.y; w2 = w4.z; w3 = w4.w;
        } else {
            w0 = __expf(lrelu(als[i0] + aldn));
            w1 = __expf(lrelu(als[i1] + aldn));
            w2 = __expf(lrelu(als[i2] + aldn));
            w3 = __expf(lrelu(als[i3] + aldn));
        }
        float2 f0 = h2p[(size_t)i0 * 8 + l];
        float2 f1 = h2p[(size_t)i1 * 8 + l];
        float2 f2 = h2p[(size_t)i2 * 8 + l];
        float2 f3 = h2p[(size_t)i3 * 8 + l];
        s0x += w0 * f0.x; s0y += w0 * f0.y;
        s1x += w1 * f1.x; s1y += w1 * f1.y;
        s2x += w2 * f2.x; s2y += w2 * f2.y;
        s3x += w3 * f3.x; s3y += w3 * f3.y;
        den += (w0 + w1) + (w2 + w3);
    }
    for (; e < e1; ++e) {                      // tail
        int word = csr[e];
        int s = word & SRCMASK;
        float we;
        if constexpr (HASW) we = wbuf[e];
        else we = __expf(lrelu(als[s] + aldn));
        float2 f = h2p[(size_t)s * 8 + l];
        s0x += we * f.x; s0y += we * f.y;
        den += we;
    }
    float inv = 1.0f / den;
    float2 r;
    r.x = (s0x + s1x + s2x + s3x) * inv + b2[2 * l];
    r.y = (s0y + s1y + s2y + s3y) * inv + b2[2 * l + 1];
    ((float2*)out)[(size_t)n * 8 + l] = r;
}

extern "C" void kernel_launch(void* const* d_in, const int* in_sizes, int n_in,
                              void* d_out, int out_size, void* d_ws, size_t ws_size,
                              hipStream_t stream)
{
    const float* x   = (const float*)d_in[0];
    const int*   ei  = (const int*)d_in[1];
    // d_in[2] = ew, unused (edge_dim=None)
    const float* W1  = (const float*)d_in[3];
    const float* as1 = (const float*)d_in[4];
    const float* ad1 = (const float*)d_in[5];
    const float* b1  = (const float*)d_in[6];
    const float* W2  = (const float*)d_in[7];
    const float* as2 = (const float*)d_in[8];
    const float* ad2 = (const float*)d_in[9];
    const float* b2  = (const float*)d_in[10];
    float* out = (float*)d_out;

    const int Nn = in_sizes[0] / FEAT;   // 100000
    const int E_ = in_sizes[1] / 2;      // 3200000
    const int nb = (Nn + BIN_NODES - 1) >> BSH;   // 391

    // workspace layout
    float* h1    = (float*)d_ws;                  // Nn*32 (also CSR-build scratch)
    float* als1  = h1 + (size_t)Nn * HID;         // Nn
    float* ald1  = als1 + Nn;                     // Nn
    float* h2    = ald1 + Nn;                     // Nn*16
    float* als2p = h2 + (size_t)Nn * EMB;         // Nn
    float* ald2p = als2p + Nn;                    // Nn
    int* rowptr  = (int*)(ald2p + Nn);            // Nn+1
    int* binCnt  = rowptr + Nn + 1;               // NBMAX
    int* binstart= binCnt + NBMAX;                // NBMAX+1
    int* bin_pos = binstart + NBMAX + 1;          // NBMAX
    int* packedr = bin_pos + NBMAX;               // E_ (full words; csr in place)
    int* packed  = (int*)(((uintptr_t)packedr + 15) & ~(uintptr_t)15); // 16B align
    float* wbuf  = (float*)(packed + E_);         // E_ (per-edge weights, 16B-al.)
    size_t need  = (size_t)((char*)(wbuf + E_) - (char*)d_ws);
    bool hasw    = ws_size >= need;               // fallback: inline-exp kernels

    // ---- build CSR (by destination) via binned counting sort ----
    k_zero_int<<<(nb + 255) / 256, 256, 0, stream>>>(binCnt, nb);
    k_bincnt<<<1024, 256, 0, stream>>>(ei, E_, Nn, binCnt);
    k_binscan<<<1, 512, 0, stream>>>(binCnt, binstart, bin_pos, rowptr, Nn, E_);
    k_part<<<(E_ + CH - 1) / CH, 1024, 0, stream>>>(ei, E_, Nn, bin_pos, packed);
    k_build<<<nb, 1024, 0, stream>>>(binstart, Nn, E_, packed, rowptr, (int*)h1);

    // ---- layer 1 ----
    k_h1<<<(Nn + 255) / 256, 256, 0, stream>>>(x, W1, as1, ad1, h1, als1, ald1, Nn);
    if (hasw) {
        k_wgt<<<nb, 1024, 0, stream>>>(binstart, packed, als1, ald1, wbuf);
        k_agg1<true><<<(Nn + 31) / 32, 256, 0, stream>>>(rowptr, packed, wbuf,
            h1, als1, ald1, b1, W2, as2, ad2, h2, als2p, ald2p, Nn);
        k_wgt<<<nb, 1024, 0, stream>>>(binstart, packed, als2p, ald2p, wbuf);
        k_agg2<true><<<(Nn + 31) / 32, 256, 0, stream>>>(rowptr, packed, wbuf,
            h2, als2p, ald2p, b2, out, Nn);
    } else {
        k_agg1<false><<<(Nn + 31) / 32, 256, 0, stream>>>(rowptr, packed, nullptr,
            h1, als1, ald1, b1, W2, as2, ad2, h2, als2p, ald2p, Nn);
        k_agg2<false><<<(Nn + 31) / 32, 256, 0, stream>>>(rowptr, packed, nullptr,
            h2, als2p, ald2p, b2, out, Nn);
    }
}

// Round 9
// 297.553 us; speedup vs baseline: 1.2205x; 1.2205x over previous
//
#include <hip/hip_runtime.h>
#include <hip/hip_fp16.h>

#define FEAT 128
#define HID 32
#define EMB 16
#define NEG 0.2f

// CSR-build binning parameters. Assumes Nn <= 2^17 (src id fits 17 bits) and
// Nn <= NBMAX*BIN_NODES. For this problem Nn=100000, E=3.2M.
#define BSH 8                 // 256 nodes per bin
#define BIN_NODES 256
#define NBMAX 400             // >= ceil(100000/256)=391
#define CH 8192               // edges per partition block
#define SRCBITS 17
#define SRCMASK 0x1FFFF

__device__ __forceinline__ float lrelu(float a) { return a > 0.0f ? a : NEG * a; }

__global__ __launch_bounds__(256) void k_zero_int(int* p, int n) {
    int i = (int)(blockIdx.x * 256 + threadIdx.x);
    if (i < n) p[i] = 0;
}

// ---- CSR phase 1 FUSED with layer-1 GEMM: per-bin edge counts + h1 row per
// thread. The two are data-independent; fusing hides the GEMM under the
// histogram's memory phase. h1 stored FP16 (gather payload halving); als/ald
// stay fp32. W1 accesses are wave-uniform -> s_load; no LDS for the GEMM.
__global__ __launch_bounds__(256) void k_bincnt_h1(
    const int* __restrict__ ei, int E_, int Nn, int* __restrict__ binCnt,
    const float* __restrict__ x, const float* __restrict__ W1,
    const float* __restrict__ a_s, const float* __restrict__ a_d,
    __half* __restrict__ h1h, float* __restrict__ als, float* __restrict__ ald)
{
    __shared__ int h[NBMAX];
    int nb = (Nn + BIN_NODES - 1) >> BSH;
    for (int i = threadIdx.x; i < nb; i += 256) h[i] = 0;
    __syncthreads();
    int tid = (int)(blockIdx.x * 256 + threadIdx.x);
    if (tid < Nn) {
        const float4* xr = (const float4*)(x + (size_t)tid * FEAT);
        float acc[HID];
#pragma unroll
        for (int c = 0; c < HID; ++c) acc[c] = 0.0f;
#pragma unroll 4
        for (int k4 = 0; k4 < FEAT / 4; ++k4) {
            float4 xv = xr[k4];
            const float* Wr = W1 + k4 * 4 * HID;   // wave-uniform -> s_load
#pragma unroll
            for (int c = 0; c < HID; ++c)
                acc[c] += xv.x * Wr[c] + xv.y * Wr[HID + c]
                        + xv.z * Wr[2 * HID + c] + xv.w * Wr[3 * HID + c];
        }
        float ps = 0.0f, pd = 0.0f;
        __half hb[HID];
#pragma unroll
        for (int c = 0; c < HID; ++c) {
            ps += acc[c] * a_s[c];
            pd += acc[c] * a_d[c];
            hb[c] = __float2half(acc[c]);
        }
        int4* dst = (int4*)(h1h + (size_t)tid * HID);   // 64 B row, 16B-aligned
        const int4* sb = (const int4*)hb;
        dst[0] = sb[0]; dst[1] = sb[1]; dst[2] = sb[2]; dst[3] = sb[3];
        als[tid] = ps;
        ald[tid] = pd;
    }
    int stride = (int)(gridDim.x * 256);
    for (int i = tid; i < E_; i += stride)
        atomicAdd(&h[ei[(size_t)E_ + i] >> BSH], 1);
    __syncthreads();
    for (int i = threadIdx.x; i < nb; i += 256)
        if (h[i]) atomicAdd(&binCnt[i], h[i]);
}

// ---- phase 2: scan bin counts -> binstart, init bin_pos; rowptr[Nn]=E ----
__global__ __launch_bounds__(512) void k_binscan(const int* __restrict__ binCnt,
                                                 int* __restrict__ binstart,
                                                 int* __restrict__ bin_pos,
                                                 int* __restrict__ rowptr,
                                                 int Nn, int E_) {
    __shared__ int s[512];
    int nb = (Nn + BIN_NODES - 1) >> BSH;
    int t = (int)threadIdx.x;
    s[t] = (t < nb) ? binCnt[t] : 0;
    __syncthreads();
    for (int off = 1; off < 512; off <<= 1) {
        int v = (t >= off) ? s[t - off] : 0;
        __syncthreads();
        s[t] += v;
        __syncthreads();
    }
    if (t <= nb) binstart[t] = (t == 0) ? 0 : s[t - 1];
    if (t < nb) bin_pos[t] = (t == 0) ? 0 : s[t - 1];
    if (t == 0) rowptr[Nn] = E_;
}

// ---- phase 3: multisplit partition. Stage chunk in LDS grouped by bin, then
// write contiguous per-bin runs of packed words ((dst&255)<<17 | src). ----
__global__ __launch_bounds__(1024) void k_part(const int* __restrict__ ei, int E_,
                                               int Nn, int* __restrict__ bin_pos,
                                               int* __restrict__ packed) {
    __shared__ int hist[NBMAX];
    __shared__ int lofs[NBMAX];
    __shared__ int pos[NBMAX];
    __shared__ int gbase[NBMAX];
    __shared__ int sscan[512];
    __shared__ int staged[CH];
    __shared__ unsigned short sbin[CH];
    int nb = (Nn + BIN_NODES - 1) >> BSH;
    int base = (int)(blockIdx.x * CH);
    int nE = min(CH, E_ - base);
    int t = (int)threadIdx.x;
    for (int i = t; i < nb; i += 1024) hist[i] = 0;
    __syncthreads();

    int myw[CH / 1024];
    int myb[CH / 1024];
#pragma unroll
    for (int k = 0; k < CH / 1024; ++k) {
        int i = t + k * 1024;
        int w = 0, b_ = -1;
        if (i < nE) {
            int s_ = ei[base + i];
            int d_ = ei[(size_t)E_ + base + i];
            b_ = d_ >> BSH;
            w = ((d_ & (BIN_NODES - 1)) << SRCBITS) | s_;
            atomicAdd(&hist[b_], 1);
        }
        myw[k] = w;
        myb[k] = b_;
    }
    __syncthreads();
    // exclusive scan of hist over 512-wide region
    if (t < 512) sscan[t] = (t < nb) ? hist[t] : 0;
    __syncthreads();
    for (int off = 1; off < 512; off <<= 1) {
        int v = 0;
        if (t < 512 && t >= off) v = sscan[t - off];
        __syncthreads();
        if (t < 512) sscan[t] += v;
        __syncthreads();
    }
    for (int i = t; i < nb; i += 1024) {
        int ex = (i == 0) ? 0 : sscan[i - 1];
        lofs[i] = ex;
        pos[i] = ex;
    }
    __syncthreads();
    // scatter into LDS grouped by bin
#pragma unroll
    for (int k = 0; k < CH / 1024; ++k) {
        if (myb[k] >= 0) {
            int p = atomicAdd(&pos[myb[k]], 1);
            staged[p] = myw[k];
            sbin[p] = (unsigned short)myb[k];
        }
    }
    __syncthreads();
    // reserve global runs (one atomic per non-empty bin)
    for (int i = t; i < nb; i += 1024)
        gbase[i] = hist[i] ? atomicAdd(&bin_pos[i], hist[i]) : 0;
    __syncthreads();
    // coalesced write-out of per-bin runs
    for (int i = t; i < nE; i += 1024) {
        int b_ = sbin[i];
        packed[gbase[b_] + (i - lofs[b_])] = staged[i];
    }
}

// ---- phase 4: per-bin build, OUT-OF-PLACE (packed -> csr). Per-node hist +
// scan in LDS, then direct global scatter: each bin's output span is ~48 KB
// (L2-hot), so no LDS bounce and no capacity/overflow path is needed. ----
__global__ __launch_bounds__(1024) void k_build(const int* __restrict__ binstart,
                                                int Nn,
                                                const int* __restrict__ packed,
                                                int* __restrict__ csr,
                                                int* __restrict__ rowptr) {
    __shared__ int ncnt[BIN_NODES];
    __shared__ int npos[BIN_NODES];
    __shared__ int sscan[BIN_NODES];
    int b = (int)blockIdx.x;
    int s = binstart[b], e = binstart[b + 1];
    int cnt = e - s;
    int nb0 = b << BSH;
    int nodes = min(BIN_NODES, Nn - nb0);
    int t = (int)threadIdx.x;
    if (t < BIN_NODES) ncnt[t] = 0;
    __syncthreads();
    for (int i = t; i < cnt; i += 1024)
        atomicAdd(&ncnt[(packed[s + i] >> SRCBITS) & 255], 1);
    __syncthreads();
    if (t < BIN_NODES) sscan[t] = ncnt[t];
    __syncthreads();
    for (int off = 1; off < BIN_NODES; off <<= 1) {
        int v = 0;
        if (t < BIN_NODES && t >= off) v = sscan[t - off];
        __syncthreads();
        if (t < BIN_NODES) sscan[t] += v;
        __syncthreads();
    }
    if (t < BIN_NODES) {
        int ex = (t == 0) ? 0 : sscan[t - 1];
        npos[t] = ex;
        if (t < nodes) rowptr[nb0 + t] = s + ex;
    }
    __syncthreads();
    for (int i = t; i < cnt; i += 1024) {
        int w = packed[s + i];
        int p = atomicAdd(&npos[(w >> SRCBITS) & 255], 1);
        csr[s + p] = w & SRCMASK;
    }
}

// layer-1 gather-aggregate + norm + relu + (g @ W2) + als2/ald2, fused.
// 8 lanes per node, each lane owns 4 FP16 features (8 B/lane). Edge loop
// unrolled 4x (four independent gather chains); inline exp (r8 proved the
// kernel is gather-bound, wbuf only added traffic). Accumulation fp32.
__global__ __launch_bounds__(256) void k_agg1(
    const int* __restrict__ rowptr, const int* __restrict__ csr,
    const __half* __restrict__ h1h, const float* __restrict__ als,
    const float* __restrict__ ald, const float* __restrict__ b1,
    const float* __restrict__ W2, const float* __restrict__ a_s2,
    const float* __restrict__ a_d2,
    __half* __restrict__ h2h, float* __restrict__ als2, float* __restrict__ ald2,
    int Nn)
{
    int n = (int)(blockIdx.x * 32 + (threadIdx.x >> 3));
    if (n >= Nn) return;
    int l = threadIdx.x & 7;                   // lane in 8-lane group
    const __half* h1b = h1h + 4 * l;           // lane's feature offset
    float aldn = ald[n];
    float wself = __expf(lrelu(als[n] + aldn));
    uint2 rs = *(const uint2*)(h1b + (size_t)n * HID);
    float2 pa = __half22float2(*reinterpret_cast<const __half2*>(&rs.x));
    float2 pb = __half22float2(*reinterpret_cast<const __half2*>(&rs.y));
    float s0x = wself * pa.x, s0y = wself * pa.y;
    float s0z = wself * pb.x, s0w = wself * pb.y;
    float s1x = 0, s1y = 0, s1z = 0, s1w = 0;
    float s2x = 0, s2y = 0, s2z = 0, s2w = 0;
    float s3x = 0, s3y = 0, s3z = 0, s3w = 0;
    float den = wself;
    int e = rowptr[n], e1 = rowptr[n + 1];
    for (; e + 4 <= e1; e += 4) {
        int i0 = csr[e + 0];
        int i1 = csr[e + 1];
        int i2 = csr[e + 2];
        int i3 = csr[e + 3];
        uint2 g0 = *(const uint2*)(h1b + (size_t)i0 * HID);
        uint2 g1 = *(const uint2*)(h1b + (size_t)i1 * HID);
        uint2 g2 = *(const uint2*)(h1b + (size_t)i2 * HID);
        uint2 g3 = *(const uint2*)(h1b + (size_t)i3 * HID);
        float a0 = als[i0], a1 = als[i1], a2 = als[i2], a3 = als[i3];
        float w0 = __expf(lrelu(a0 + aldn));
        float w1 = __expf(lrelu(a1 + aldn));
        float w2 = __expf(lrelu(a2 + aldn));
        float w3 = __expf(lrelu(a3 + aldn));
        float2 f0a = __half22float2(*reinterpret_cast<const __half2*>(&g0.x));
        float2 f0b = __half22float2(*reinterpret_cast<const __half2*>(&g0.y));
        float2 f1a = __half22float2(*reinterpret_cast<const __half2*>(&g1.x));
        float2 f1b = __half22float2(*reinterpret_cast<const __half2*>(&g1.y));
        float2 f2a = __half22float2(*reinterpret_cast<const __half2*>(&g2.x));
        float2 f2b = __half22float2(*reinterpret_cast<const __half2*>(&g2.y));
        float2 f3a = __half22float2(*reinterpret_cast<const __half2*>(&g3.x));
        float2 f3b = __half22float2(*reinterpret_cast<const __half2*>(&g3.y));
        s0x += w0 * f0a.x; s0y += w0 * f0a.y; s0z += w0 * f0b.x; s0w += w0 * f0b.y;
        s1x += w1 * f1a.x; s1y += w1 * f1a.y; s1z += w1 * f1b.x; s1w += w1 * f1b.y;
        s2x += w2 * f2a.x; s2y += w2 * f2a.y; s2z += w2 * f2b.x; s2w += w2 * f2b.y;
        s3x += w3 * f3a.x; s3y += w3 * f3a.y; s3z += w3 * f3b.x; s3w += w3 * f3b.y;
        den += (w0 + w1) + (w2 + w3);
    }
    for (; e < e1; ++e) {
        int s = csr[e];
        float we = __expf(lrelu(als[s] + aldn));
        uint2 g = *(const uint2*)(h1b + (size_t)s * HID);
        float2 fa = __half22float2(*reinterpret_cast<const __half2*>(&g.x));
        float2 fb = __half22float2(*reinterpret_cast<const __half2*>(&g.y));
        s0x += we * fa.x; s0y += we * fa.y; s0z += we * fb.x; s0w += we * fb.y;
        den += we;
    }
    float inv = 1.0f / den;
    float gx = fmaxf((s0x + s1x + s2x + s3x) * inv + b1[4 * l + 0], 0.0f);
    float gy = fmaxf((s0y + s1y + s2y + s3y) * inv + b1[4 * l + 1], 0.0f);
    float gz = fmaxf((s0z + s1z + s2z + s3z) * inv + b1[4 * l + 2], 0.0f);
    float gw = fmaxf((s0w + s1w + s2w + s3w) * inv + b1[4 * l + 3], 0.0f);
    // h2[n][j] = sum_t g[t] * W2[t][j]; lane l computes cols l and l+8.
    float hc0 = 0.0f, hc1 = 0.0f;
#pragma unroll
    for (int tt = 0; tt < 8; ++tt) {
        float bx = __shfl(gx, tt, 8);
        float by = __shfl(gy, tt, 8);
        float bz = __shfl(gz, tt, 8);
        float bw = __shfl(gw, tt, 8);
        const float* wp = &W2[(4 * tt) * EMB];
        hc0 += bx * wp[l] + by * wp[EMB + l]
             + bz * wp[2 * EMB + l] + bw * wp[3 * EMB + l];
        hc1 += bx * wp[l + 8] + by * wp[EMB + l + 8]
             + bz * wp[2 * EMB + l + 8] + bw * wp[3 * EMB + l + 8];
    }
    h2h[(size_t)n * EMB + l]     = __float2half(hc0);
    h2h[(size_t)n * EMB + l + 8] = __float2half(hc1);
    float ps = hc0 * a_s2[l] + hc1 * a_s2[l + 8];
    float pd = hc0 * a_d2[l] + hc1 * a_d2[l + 8];
    for (int m = 1; m < 8; m <<= 1) {
        ps += __shfl_xor(ps, m, 8);
        pd += __shfl_xor(pd, m, 8);
    }
    if (l == 0) { als2[n] = ps; ald2[n] = pd; }
}

// layer-2 gather-aggregate + bias. 8 lanes per node (r6's winning shape),
// FP16 h2 rows = 32 B -> the 3.2 MB table is L2-resident. Output fp32.
__global__ __launch_bounds__(256) void k_agg2(
    const int* __restrict__ rowptr, const int* __restrict__ csr,
    const __half* __restrict__ h2h, const float* __restrict__ als,
    const float* __restrict__ ald, const float* __restrict__ b2,
    float* __restrict__ out, int Nn)
{
    int n = (int)(blockIdx.x * 32 + (threadIdx.x >> 3));
    if (n >= Nn) return;
    int l = threadIdx.x & 7;                   // lane in 8-lane group
    const __half* h2b = h2h + 2 * l;
    float aldn = ald[n];
    float wself = __expf(lrelu(als[n] + aldn));
    float2 sv = __half22float2(*(const __half2*)(h2b + (size_t)n * EMB));
    float s0x = wself * sv.x, s0y = wself * sv.y;
    float s1x = 0, s1y = 0, s2x = 0, s2y = 0, s3x = 0, s3y = 0;
    float den = wself;
    int e = rowptr[n], e1 = rowptr[n + 1];
    for (; e + 4 <= e1; e += 4) {
        int i0 = csr[e + 0];
        int i1 = csr[e + 1];
        int i2 = csr[e + 2];
        int i3 = csr[e + 3];
        float2 f0 = __half22float2(*(const __half2*)(h2b + (size_t)i0 * EMB));
        float2 f1 = __half22float2(*(const __half2*)(h2b + (size_t)i1 * EMB));
        float2 f2 = __half22float2(*(const __half2*)(h2b + (size_t)i2 * EMB));
        float2 f3 = __half22float2(*(const __half2*)(h2b + (size_t)i3 * EMB));
        float a0 = als[i0], a1 = als[i1], a2 = als[i2], a3 = als[i3];
        float w0 = __expf(lrelu(a0 + aldn));
        float w1 = __expf(lrelu(a1 + aldn));
        float w2 = __expf(lrelu(a2 + aldn));
        float w3 = __expf(lrelu(a3 + aldn));
        s0x += w0 * f0.x; s0y += w0 * f0.y;
        s1x += w1 * f1.x; s1y += w1 * f1.y;
        s2x += w2 * f2.x; s2y += w2 * f2.y;
        s3x += w3 * f3.x; s3y += w3 * f3.y;
        den += (w0 + w1) + (w2 + w3);
    }
    for (; e < e1; ++e) {
        int s = csr[e];
        float we = __expf(lrelu(als[s] + aldn));
        float2 f = __half22float2(*(const __half2*)(h2b + (size_t)s * EMB));
        s0x += we * f.x; s0y += we * f.y;
        den += we;
    }
    float inv = 1.0f / den;
    float2 r;
    r.x = (s0x + s1x + s2x + s3x) * inv + b2[2 * l];
    r.y = (s0y + s1y + s2y + s3y) * inv + b2[2 * l + 1];
    *(float2*)(out + (size_t)n * EMB + 2 * l) = r;
}

extern "C" void kernel_launch(void* const* d_in, const int* in_sizes, int n_in,
                              void* d_out, int out_size, void* d_ws, size_t ws_size,
                              hipStream_t stream)
{
    const float* x   = (const float*)d_in[0];
    const int*   ei  = (const int*)d_in[1];
    // d_in[2] = ew, unused (edge_dim=None)
    const float* W1  = (const float*)d_in[3];
    const float* as1 = (const float*)d_in[4];
    const float* ad1 = (const float*)d_in[5];
    const float* b1  = (const float*)d_in[6];
    const float* W2  = (const float*)d_in[7];
    const float* as2 = (const float*)d_in[8];
    const float* ad2 = (const float*)d_in[9];
    const float* b2  = (const float*)d_in[10];
    float* out = (float*)d_out;

    const int Nn = in_sizes[0] / FEAT;   // 100000
    const int E_ = in_sizes[1] / 2;      // 3200000
    const int nb = (Nn + BIN_NODES - 1) >> BSH;   // 391

    // workspace layout (~37.3 MB; r8's hasw branch proved ws_size >= ~47 MB)
    __half* h1h   = (__half*)d_ws;                      // Nn*32 fp16 (64 B rows)
    float* als1   = (float*)(h1h + (size_t)Nn * HID);   // Nn
    float* ald1   = als1 + Nn;                          // Nn
    __half* h2h   = (__half*)(ald1 + Nn);               // Nn*16 fp16 (32 B rows)
    float* als2p  = (float*)(h2h + (size_t)Nn * EMB);   // Nn
    float* ald2p  = als2p + Nn;                         // Nn
    int* rowptr   = (int*)(ald2p + Nn);                 // Nn+1
    int* binCnt   = rowptr + Nn + 1;                    // NBMAX
    int* binstart = binCnt + NBMAX;                     // NBMAX+1
    int* bin_pos  = binstart + NBMAX + 1;               // NBMAX
    int* packed   = bin_pos + NBMAX;                    // E_ (bin-grouped words)
    int* csr      = packed + E_;                        // E_ (final CSR src ids)

    // ---- build CSR (by destination) via binned counting sort; layer-1 GEMM
    // fused into the histogram pass (independent work) ----
    k_zero_int<<<(nb + 255) / 256, 256, 0, stream>>>(binCnt, nb);
    int gb1 = (Nn + 255) / 256;
    if (gb1 < 1024) gb1 = 1024;
    k_bincnt_h1<<<gb1, 256, 0, stream>>>(ei, E_, Nn, binCnt,
                                         x, W1, as1, ad1, h1h, als1, ald1);
    k_binscan<<<1, 512, 0, stream>>>(binCnt, binstart, bin_pos, rowptr, Nn, E_);
    k_part<<<(E_ + CH - 1) / CH, 1024, 0, stream>>>(ei, E_, Nn, bin_pos, packed);
    k_build<<<nb, 1024, 0, stream>>>(binstart, Nn, packed, csr, rowptr);

    // ---- layer 1 aggregate (+fused layer-2 transform) ----
    k_agg1<<<(Nn + 31) / 32, 256, 0, stream>>>(rowptr, csr, h1h, als1, ald1,
                                               b1, W2, as2, ad2,
                                               h2h, als2p, ald2p, Nn);
    // ---- layer 2 aggregate ----
    k_agg2<<<(Nn + 31) / 32, 256, 0, stream>>>(rowptr, csr, h2h, als2p, ald2p,
                                               b2, out, Nn);
}